// Round 1
// baseline (295.360 us; speedup 1.0000x reference)
//
#include <hip/hip_runtime.h>
#include <math.h>

// Problem dims (fixed by reference)
#define BDIM 4
#define TDIM 4096
#define DDIM 1024
#define MDIM (BDIM * TDIM)   // 16384

// scan chunking
#define NC  64
#define LCH 64
static_assert(NC * LCH == TDIM, "chunking");

// GEMM tiling
#define BM 128
#define BN 128
#define BKK 64

typedef __attribute__((ext_vector_type(8))) short short8;
typedef __attribute__((ext_vector_type(4))) float f32x4;

__device__ __forceinline__ unsigned short f2bf(float f) {
  unsigned int u = __float_as_uint(f);
  unsigned int r = (u + 0x7fffu + ((u >> 16) & 1u)) >> 16;  // RNE
  return (unsigned short)r;
}
__device__ __forceinline__ float bf2f(unsigned short h) {
  return __uint_as_float(((unsigned int)h) << 16);
}
__device__ __forceinline__ float sigmoidf_(float x) {
  return 1.0f / (1.0f + expf(-x));
}

// ---------------- prep: x -> hi/lo bf16 ----------------
__global__ __launch_bounds__(256) void prep_x_kernel(const float* __restrict__ x,
                                                     unsigned short* __restrict__ xh,
                                                     unsigned short* __restrict__ xl,
                                                     int n4) {
  int i = blockIdx.x * 256 + threadIdx.x;
  if (i >= n4) return;
  float4 f = ((const float4*)x)[i];
  ushort4 h, l;
  h.x = f2bf(f.x); l.x = f2bf(f.x - bf2f(h.x));
  h.y = f2bf(f.y); l.y = f2bf(f.y - bf2f(h.y));
  h.z = f2bf(f.z); l.z = f2bf(f.z - bf2f(h.z));
  h.w = f2bf(f.w); l.w = f2bf(f.w - bf2f(h.w));
  ((ushort4*)xh)[i] = h;
  ((ushort4*)xl)[i] = l;
}

// ---------------- prep: W [K][N] f32 -> transposed [N][K] hi/lo bf16 ----------------
__global__ __launch_bounds__(256) void wprep_kernel(const float* __restrict__ in,
                                                    unsigned short* __restrict__ oh,
                                                    unsigned short* __restrict__ ol,
                                                    int K, int N) {
  __shared__ float t[64][65];  // +1 pad: conflict-free transposed read
  int n0 = blockIdx.x * 64;
  int k0 = blockIdx.y * 64;
#pragma unroll
  for (int i = 0; i < 16; ++i) {
    int idx = i * 256 + threadIdx.x;
    int r = idx >> 6, c = idx & 63;
    t[r][c] = in[(size_t)(k0 + r) * N + (n0 + c)];
  }
  __syncthreads();
#pragma unroll
  for (int i = 0; i < 16; ++i) {
    int idx = i * 256 + threadIdx.x;
    int rn = idx >> 6, ck = idx & 63;
    float f = t[ck][rn];
    unsigned short h = f2bf(f);
    size_t o = (size_t)(n0 + rn) * K + (k0 + ck);
    oh[o] = h;
    if (ol) ol[o] = f2bf(f - bf2f(h));
  }
}

// ---------------- GEMM (A [M][K] bf16, B [N][K] bf16 transposed) ----------------
// stage a 128x64 bf16 tile (16 KB) via global_load_lds, linear LDS layout [128][64]
__device__ __forceinline__ void stage_tile(const unsigned short* __restrict__ gtile,
                                           unsigned short* ldsbase, int ldK) {
  int wave = threadIdx.x >> 6;
  int lane = threadIdx.x & 63;
#pragma unroll
  for (int i = 0; i < 4; ++i) {
    int chunk = wave * 4 + i;  // 0..15, 8 rows (of 128B) per 1KB chunk
    const unsigned short* src =
        gtile + (size_t)(chunk * 8 + (lane >> 3)) * ldK + (lane & 7) * 8;
    unsigned short* dst = ldsbase + chunk * 512;  // wave-uniform base; HW adds lane*16B
    __builtin_amdgcn_global_load_lds(
        (const __attribute__((address_space(1))) unsigned int*)src,
        (__attribute__((address_space(3))) unsigned int*)dst, 16, 0, 0);
  }
}

// EPI: 0 = f32 + bias, 1 = bf16(sigmoid(+bias))
template <bool COMP, int EPI>
__global__ __launch_bounds__(256, 2) void gemm_kernel(
    const unsigned short* __restrict__ Ah, const unsigned short* __restrict__ Al,
    const unsigned short* __restrict__ Bh, const unsigned short* __restrict__ Bl,
    const float* __restrict__ bias, void* __restrict__ outp, int N, int K) {
  __shared__ unsigned short lds[(COMP ? 4 : 2) * BM * BKK];
  unsigned short* ldsAh = lds;
  unsigned short* ldsBh = lds + BM * BKK;
  unsigned short* ldsAl = lds + 2 * BM * BKK;
  unsigned short* ldsBl = lds + 3 * BM * BKK;

  int mtile = blockIdx.y, ntile = blockIdx.x;
  int wave = threadIdx.x >> 6, lane = threadIdx.x & 63;
  int wm = wave >> 1, wn = wave & 1;  // 2x2 waves, each 64x64

  f32x4 acc[4][4] = {};

  const unsigned short* Atile = Ah + (size_t)(mtile * BM) * K;
  const unsigned short* Btile = Bh + (size_t)(ntile * BN) * K;

  for (int k0 = 0; k0 < K; k0 += BKK) {
    stage_tile(Atile + k0, ldsAh, K);
    stage_tile(Btile + k0, ldsBh, K);
    if constexpr (COMP) {
      stage_tile(Al + (size_t)(mtile * BM) * K + k0, ldsAl, K);
      stage_tile(Bl + (size_t)(ntile * BN) * K + k0, ldsBl, K);
    }
    __syncthreads();  // drains vmcnt before barrier (m97 structure)

#pragma unroll
    for (int kk = 0; kk < 2; ++kk) {
      int koff = kk * 32 + (lane >> 4) * 8;
      short8 ah[4], bh[4];
#pragma unroll
      for (int m = 0; m < 4; ++m)
        ah[m] = *(const short8*)&ldsAh[(size_t)(wm * 64 + m * 16 + (lane & 15)) * BKK + koff];
#pragma unroll
      for (int n = 0; n < 4; ++n)
        bh[n] = *(const short8*)&ldsBh[(size_t)(wn * 64 + n * 16 + (lane & 15)) * BKK + koff];
      if constexpr (COMP) {
        short8 al[4], bl[4];
#pragma unroll
        for (int m = 0; m < 4; ++m)
          al[m] = *(const short8*)&ldsAl[(size_t)(wm * 64 + m * 16 + (lane & 15)) * BKK + koff];
#pragma unroll
        for (int n = 0; n < 4; ++n)
          bl[n] = *(const short8*)&ldsBl[(size_t)(wn * 64 + n * 16 + (lane & 15)) * BKK + koff];
#pragma unroll
        for (int m = 0; m < 4; ++m)
#pragma unroll
          for (int n = 0; n < 4; ++n) {
            acc[m][n] = __builtin_amdgcn_mfma_f32_16x16x32_bf16(al[m], bh[n], acc[m][n], 0, 0, 0);
            acc[m][n] = __builtin_amdgcn_mfma_f32_16x16x32_bf16(ah[m], bl[n], acc[m][n], 0, 0, 0);
            acc[m][n] = __builtin_amdgcn_mfma_f32_16x16x32_bf16(ah[m], bh[n], acc[m][n], 0, 0, 0);
          }
      } else {
#pragma unroll
        for (int m = 0; m < 4; ++m)
#pragma unroll
          for (int n = 0; n < 4; ++n)
            acc[m][n] = __builtin_amdgcn_mfma_f32_16x16x32_bf16(ah[m], bh[n], acc[m][n], 0, 0, 0);
      }
    }
    __syncthreads();
  }

  // epilogue: C/D layout col = lane&15, row = (lane>>4)*4 + j
  int col0 = ntile * BN + wn * 64 + (lane & 15);
  int row0 = mtile * BM + wm * 64 + ((lane >> 4) << 2);
#pragma unroll
  for (int n = 0; n < 4; ++n) {
    int col = col0 + n * 16;
    float bv = bias[col];
#pragma unroll
    for (int m = 0; m < 4; ++m) {
#pragma unroll
      for (int j = 0; j < 4; ++j) {
        int row = row0 + m * 16 + j;
        float val = acc[m][n][j] + bv;
        if constexpr (EPI == 0) {
          ((float*)outp)[(size_t)row * N + col] = val;
        } else {
          ((unsigned short*)outp)[(size_t)row * N + col] = f2bf(sigmoidf_(val));
        }
      }
    }
  }
}

// ---------------- SSM chunked scan ----------------
// phase 1: per-chunk local scan final (starting from h=0)
__global__ __launch_bounds__(256) void ssm_phase1(const float* __restrict__ v,
                                                  const float* __restrict__ A,
                                                  float* __restrict__ chunkh) {
  int b = blockIdx.y, c = blockIdx.x;
  int d0 = threadIdx.x * 4;
  float4 a4 = *(const float4*)&A[d0];
  float dx = sigmoidf_(a4.x), dy = sigmoidf_(a4.y), dz = sigmoidf_(a4.z), dw = sigmoidf_(a4.w);
  float hx = 0.f, hy = 0.f, hz = 0.f, hw = 0.f;
  const float4* vp = (const float4*)(v + ((size_t)b * TDIM + (size_t)c * LCH) * DDIM + d0);
#pragma unroll 4
  for (int i = 0; i < LCH; ++i) {
    float4 vv = vp[(size_t)i * (DDIM / 4)];
    hx = fmaf(dx, hx, vv.x);
    hy = fmaf(dy, hy, vv.y);
    hz = fmaf(dz, hz, vv.z);
    hw = fmaf(dw, hw, vv.w);
  }
  float4 o = {hx, hy, hz, hw};
  *(float4*)&chunkh[(size_t)(b * NC + c) * DDIM + d0] = o;
}

// phase 2: exclusive carry scan across chunks (in place). decay^LCH via 6 squarings (LCH=64)
__global__ __launch_bounds__(256) void ssm_phase2(const float* __restrict__ A,
                                                  float* __restrict__ chunkh) {
  int idx = blockIdx.x * 256 + threadIdx.x;  // 0..B*D-1
  int b = idx >> 10, d = idx & 1023;
  float dec = sigmoidf_(A[d]);
  float dL = dec;
#pragma unroll
  for (int i = 0; i < 6; ++i) dL *= dL;  // dec^64
  float carry = 0.f;
  for (int c = 0; c < NC; ++c) {
    float* p = &chunkh[(size_t)(b * NC + c) * DDIM + d];
    float local = *p;
    *p = carry;  // exclusive: h-state entering chunk c
    carry = fmaf(dL, carry, local);
  }
}

// phase 3: rescan with carry, emit y = gate * C * h as bf16
__global__ __launch_bounds__(256) void ssm_phase3(const float* __restrict__ v,
                                                  const unsigned short* __restrict__ g,
                                                  const float* __restrict__ A,
                                                  const float* __restrict__ C,
                                                  const float* __restrict__ chunkh,
                                                  unsigned short* __restrict__ ybf) {
  int b = blockIdx.y, c = blockIdx.x;
  int d0 = threadIdx.x * 4;
  float4 a4 = *(const float4*)&A[d0];
  float4 c4 = *(const float4*)&C[d0];
  float dx = sigmoidf_(a4.x), dy = sigmoidf_(a4.y), dz = sigmoidf_(a4.z), dw = sigmoidf_(a4.w);
  float4 h0 = *(const float4*)&chunkh[(size_t)(b * NC + c) * DDIM + d0];
  float hx = h0.x, hy = h0.y, hz = h0.z, hw = h0.w;
  size_t base = ((size_t)b * TDIM + (size_t)c * LCH) * DDIM + d0;
  const float4* vp = (const float4*)(v + base);
  const ushort4* gp = (const ushort4*)(g + base);
  ushort4* yp = (ushort4*)(ybf + base);
#pragma unroll 4
  for (int i = 0; i < LCH; ++i) {
    float4 vv = vp[(size_t)i * (DDIM / 4)];
    ushort4 gg = gp[(size_t)i * (DDIM / 4)];
    hx = fmaf(dx, hx, vv.x);
    hy = fmaf(dy, hy, vv.y);
    hz = fmaf(dz, hz, vv.z);
    hw = fmaf(dw, hw, vv.w);
    ushort4 yy;
    yy.x = f2bf(bf2f(gg.x) * c4.x * hx);
    yy.y = f2bf(bf2f(gg.y) * c4.y * hy);
    yy.z = f2bf(bf2f(gg.z) * c4.z * hz);
    yy.w = f2bf(bf2f(gg.w) * c4.w * hw);
    yp[(size_t)i * (DDIM / 4)] = yy;
  }
}

extern "C" void kernel_launch(void* const* d_in, const int* in_sizes, int n_in,
                              void* d_out, int out_size, void* d_ws, size_t ws_size,
                              hipStream_t stream) {
  const float* x = (const float*)d_in[0];
  const float* W_in = (const float*)d_in[1];
  const float* b_in = (const float*)d_in[2];
  const float* A = (const float*)d_in[3];
  const float* C = (const float*)d_in[4];
  const float* W_out = (const float*)d_in[5];
  const float* b_out = (const float*)d_in[6];
  float* out = (float*)d_out;

  // workspace carve (~213 MB total)
  char* ws = (char*)d_ws;
  const size_t MK = (size_t)MDIM * DDIM;  // 16,777,216
  unsigned short* xh = (unsigned short*)ws;   ws += MK * 2;                      // 33.5 MB
  unsigned short* xl = (unsigned short*)ws;   ws += MK * 2;                      // 33.5 MB
  unsigned short* winh = (unsigned short*)ws; ws += (size_t)2 * DDIM * DDIM * 2; // 4.2 MB
  unsigned short* winl = (unsigned short*)ws; ws += (size_t)2 * DDIM * DDIM * 2; // 4.2 MB
  unsigned short* wouth = (unsigned short*)ws; ws += (size_t)DDIM * DDIM * 2;    // 2.1 MB
  float* v = (float*)ws;                      ws += MK * 4;                      // 67.1 MB
  unsigned short* g = (unsigned short*)ws;    ws += MK * 2;                      // 33.5 MB
  unsigned short* ybf = (unsigned short*)ws;  ws += MK * 2;                      // 33.5 MB
  float* chunkh = (float*)ws;                 ws += (size_t)BDIM * NC * DDIM * 4; // 1.0 MB

  // prep
  prep_x_kernel<<<(int)(MK / 4 / 256), 256, 0, stream>>>(x, xh, xl, (int)(MK / 4));
  wprep_kernel<<<dim3(2 * DDIM / 64, DDIM / 64), 256, 0, stream>>>(W_in, winh, winl, DDIM, 2 * DDIM);
  wprep_kernel<<<dim3(DDIM / 64, DDIM / 64), 256, 0, stream>>>(W_out, wouth, nullptr, DDIM, DDIM);

  dim3 ggrid(DDIM / BN, MDIM / BM);  // (8, 128)
  // v = x @ W_in[:, :D] + b_in[:D]  (compensated bf16x2, f32 out)
  gemm_kernel<true, 0><<<ggrid, 256, 0, stream>>>(xh, xl, winh, winl, b_in, v, DDIM, DDIM);
  // g = sigmoid(x @ W_in[:, D:] + b_in[D:])  (plain bf16, bf16 out)
  gemm_kernel<false, 1><<<ggrid, 256, 0, stream>>>(xh, nullptr, winh + (size_t)DDIM * DDIM,
                                                   nullptr, b_in + DDIM, g, DDIM, DDIM);

  // chunked scan
  ssm_phase1<<<dim3(NC, BDIM), 256, 0, stream>>>(v, A, chunkh);
  ssm_phase2<<<(BDIM * DDIM) / 256, 256, 0, stream>>>(A, chunkh);
  ssm_phase3<<<dim3(NC, BDIM), 256, 0, stream>>>(v, g, A, C, chunkh, ybf);

  // out = y @ W_out + b_out  (plain bf16, f32 out)
  gemm_kernel<false, 0><<<ggrid, 256, 0, stream>>>(ybf, nullptr, wouth, nullptr, b_out, out,
                                                   DDIM, DDIM);
}

// Round 2
// 203.963 us; speedup vs baseline: 1.4481x; 1.4481x over previous
//
#include <hip/hip_runtime.h>
#include <math.h>

// Problem dims (fixed by reference)
#define BDIM 4
#define TDIM 4096
#define DDIM 1024
#define MDIM (BDIM * TDIM)   // 16384

// scan chunking
#define NC  64
#define LCH 64
static_assert(NC * LCH == TDIM, "chunking");

typedef __attribute__((ext_vector_type(8))) short short8;
typedef __attribute__((ext_vector_type(4))) float f32x4;

__device__ __forceinline__ unsigned short f2bf(float f) {
  unsigned int u = __float_as_uint(f);
  unsigned int r = (u + 0x7fffu + ((u >> 16) & 1u)) >> 16;  // RNE
  return (unsigned short)r;
}
__device__ __forceinline__ float bf2f(unsigned short h) {
  return __uint_as_float(((unsigned int)h) << 16);
}
__device__ __forceinline__ float sigmoidf_(float x) {
  return 1.0f / (1.0f + expf(-x));
}

// ---------------- prep: x -> bf16 ----------------
__global__ __launch_bounds__(256) void prep_x_kernel(const float* __restrict__ x,
                                                     unsigned short* __restrict__ xh,
                                                     int n4) {
  int i = blockIdx.x * 256 + threadIdx.x;
  if (i >= n4) return;
  float4 f = ((const float4*)x)[i];
  ushort4 h;
  h.x = f2bf(f.x);
  h.y = f2bf(f.y);
  h.z = f2bf(f.z);
  h.w = f2bf(f.w);
  ((ushort4*)xh)[i] = h;
}

// ---------------- prep: W [K][N] f32 -> transposed [N][K] bf16 ----------------
__global__ __launch_bounds__(256) void wprep_kernel(const float* __restrict__ in,
                                                    unsigned short* __restrict__ oh,
                                                    int K, int N) {
  __shared__ float t[64][65];
  int n0 = blockIdx.x * 64;
  int k0 = blockIdx.y * 64;
#pragma unroll
  for (int i = 0; i < 16; ++i) {
    int idx = i * 256 + threadIdx.x;
    int r = idx >> 6, c = idx & 63;
    t[r][c] = in[(size_t)(k0 + r) * N + (n0 + c)];
  }
  __syncthreads();
#pragma unroll
  for (int i = 0; i < 16; ++i) {
    int idx = i * 256 + threadIdx.x;
    int rn = idx >> 6, ck = idx & 63;
    oh[(size_t)(n0 + rn) * K + (k0 + ck)] = f2bf(t[ck][rn]);
  }
}

// ---------------- 256x256 8-wave GEMM, BK=64, dbuf LDS, XOR-swizzled ----------------
// LDS tile: 256 rows x 64 cols bf16 = 32KB. Swizzle: byte ^= ((row&7)<<4).
// global_load_lds dest is LINEAR; source address carries the inverse swizzle
// (involution), reads apply the same XOR (rule 21: both-sides).

__device__ __forceinline__ void stage_tile(unsigned short* ldsTile,
                                           const unsigned short* __restrict__ gTile,
                                           int ldK) {
  int wave = threadIdx.x >> 6;
  int lane = threadIdx.x & 63;
#pragma unroll
  for (int half = 0; half < 2; ++half) {
#pragma unroll
    for (int j = 0; j < 2; ++j) {
      int c = wave * 64 + lane + j * 512;          // 16B-chunk index within half
      int Lt = half * 16384 + c * 16;              // within-tile linear byte
      int P = Lt ^ (((Lt >> 7) & 7) << 4);         // logical byte (row*128+colByte)
      const unsigned short* src = gTile + (size_t)(P >> 7) * ldK + ((P & 127) >> 1);
      // dest: wave-uniform base; HW adds lane*16
      unsigned short* dst = ldsTile + (half * 16384 + wave * 1024 + j * 8192) / 2;
      __builtin_amdgcn_global_load_lds(
          (const __attribute__((address_space(1))) unsigned int*)src,
          (__attribute__((address_space(3))) unsigned int*)dst, 16, 0, 0);
    }
  }
}

__device__ __forceinline__ short8 read_frag(const unsigned short* tile, int r, int kElem) {
  int addr = ((r << 7) + (kElem << 1)) ^ ((r & 7) << 4);
  return *(const short8*)((const char*)tile + addr);
}

#define GEMM_PHASE(KK, H, STAGECODE, TAILCODE)                                  \
  {                                                                             \
    short8 af[4];                                                               \
    _Pragma("unroll") for (int m = 0; m < 4; ++m)                               \
        af[m] = read_frag(As, rA + (H) * 64 + m * 16, (KK) * 32 + kq);          \
    if ((H) == 0) {                                                             \
      _Pragma("unroll") for (int n = 0; n < 4; ++n)                             \
          bfr[n] = read_frag(Bs, rB + n * 16, (KK) * 32 + kq);                  \
    }                                                                           \
    STAGECODE                                                                   \
    asm volatile("" ::: "memory");                                              \
    __builtin_amdgcn_s_barrier();                                               \
    asm volatile("" ::: "memory");                                              \
    __builtin_amdgcn_s_setprio(1);                                              \
    _Pragma("unroll") for (int m = 0; m < 4; ++m)                               \
        _Pragma("unroll") for (int n = 0; n < 4; ++n)                           \
            acc[(H) * 4 + m][n] = __builtin_amdgcn_mfma_f32_16x16x32_bf16(      \
                af[m], bfr[n], acc[(H) * 4 + m][n], 0, 0, 0);                   \
    __builtin_amdgcn_s_setprio(0);                                              \
    TAILCODE                                                                    \
    asm volatile("" ::: "memory");                                              \
    __builtin_amdgcn_s_barrier();                                               \
  }

// EPI 0: f32 out + bias (N = nNt*256). EPI 1: fused v|g (ntile<4 -> v f32+bias,
// else g = bf16(sigmoid(+bias))), both ld 1024.
template <int EPI>
__global__ __launch_bounds__(512, 2) void gemm8p(const unsigned short* __restrict__ A,
                                                 const unsigned short* __restrict__ B,
                                                 const float* __restrict__ bias,
                                                 float* __restrict__ outF,
                                                 unsigned short* __restrict__ outG,
                                                 int nNt, int K) {
  __shared__ unsigned short ldsA[2 * 16384];
  __shared__ unsigned short ldsB[2 * 16384];

  // T1: XCD-aware swizzle (gridDim.x % 8 == 0 for all our launches)
  int cpx = gridDim.x >> 3;
  int bid = blockIdx.x;
  int swz = (bid & 7) * cpx + (bid >> 3);
  int mtile = swz / nNt, ntile = swz % nNt;

  int wave = threadIdx.x >> 6, lane = threadIdx.x & 63;
  int wm = wave >> 2, wn = wave & 3;  // 2 x 4 waves, each 128x64 output
  int rA = wm * 128 + (lane & 15);
  int rB = wn * 64 + (lane & 15);
  int kq = (lane >> 4) * 8;

  const unsigned short* Ag = A + (size_t)(mtile * 256) * K;
  const unsigned short* Bg = B + (size_t)(ntile * 256) * K;

  f32x4 acc[8][4] = {};
  short8 bfr[4];

  // prologue: stage K-tile 0 into buf 0, full drain (once)
  stage_tile(ldsA, Ag, K);
  stage_tile(ldsB, Bg, K);
  asm volatile("s_waitcnt vmcnt(0)" ::: "memory");
  __builtin_amdgcn_s_barrier();
  asm volatile("" ::: "memory");

  int NT = K >> 6;
  for (int t = 0; t < NT; ++t) {
    const unsigned short* As = ldsA + (t & 1) * 16384;
    const unsigned short* Bs = ldsB + (t & 1) * 16384;
    unsigned short* An = ldsA + ((t + 1) & 1) * 16384;
    unsigned short* Bn = ldsB + ((t + 1) & 1) * 16384;
    bool pf = (t + 1 < NT);
    int k1 = (t + 1) << 6;

    // 4 phases: (kk,h). Stages for tile t+1 go out in phases 0-1 (earliest legal
    // point: buf[t+1] freed by tile t-1's final barrier). Single counted drain
    // at the tile boundary, after ~2.5 phases of MFMA have elapsed.
    GEMM_PHASE(0, 0, { if (pf) stage_tile(An, Ag + k1, K); }, {})
    GEMM_PHASE(0, 1, { if (pf) stage_tile(Bn, Bg + k1, K); }, {})
    GEMM_PHASE(1, 0, {}, {})
    GEMM_PHASE(1, 1, {}, {
      if (pf) asm volatile("s_waitcnt vmcnt(0)" ::: "memory");
    })
  }

  // epilogue: C/D layout col = lane&15, row = (lane>>4)*4 + j
  int row0 = mtile * 256 + wm * 128 + ((lane >> 4) << 2);
  int col0 = ntile * 256 + wn * 64 + (lane & 15);
#pragma unroll
  for (int m = 0; m < 8; ++m) {
#pragma unroll
    for (int n = 0; n < 4; ++n) {
      int col = col0 + n * 16;
      float bv = bias[col];
#pragma unroll
      for (int j = 0; j < 4; ++j) {
        int row = row0 + m * 16 + j;
        float val = acc[m][n][j] + bv;
        if (EPI == 0) {
          outF[(size_t)row * (nNt * 256) + col] = val;
        } else {
          if (col < DDIM)
            outF[(size_t)row * DDIM + col] = val;
          else
            outG[(size_t)row * DDIM + (col - DDIM)] = f2bf(sigmoidf_(val));
        }
      }
    }
  }
}

// ---------------- SSM chunked scan ----------------
__global__ __launch_bounds__(256) void ssm_phase1(const float* __restrict__ v,
                                                  const float* __restrict__ A,
                                                  float* __restrict__ chunkh) {
  int b = blockIdx.y, c = blockIdx.x;
  int d0 = threadIdx.x * 4;
  float4 a4 = *(const float4*)&A[d0];
  float dx = sigmoidf_(a4.x), dy = sigmoidf_(a4.y), dz = sigmoidf_(a4.z), dw = sigmoidf_(a4.w);
  float hx = 0.f, hy = 0.f, hz = 0.f, hw = 0.f;
  const float4* vp = (const float4*)(v + ((size_t)b * TDIM + (size_t)c * LCH) * DDIM + d0);
#pragma unroll 4
  for (int i = 0; i < LCH; ++i) {
    float4 vv = vp[(size_t)i * (DDIM / 4)];
    hx = fmaf(dx, hx, vv.x);
    hy = fmaf(dy, hy, vv.y);
    hz = fmaf(dz, hz, vv.z);
    hw = fmaf(dw, hw, vv.w);
  }
  float4 o = {hx, hy, hz, hw};
  *(float4*)&chunkh[(size_t)(b * NC + c) * DDIM + d0] = o;
}

// phase 2: exclusive carry scan across chunks. Bulk-load into registers first
// (independent loads) to avoid a 64-deep dependent latency chain.
__global__ __launch_bounds__(256) void ssm_phase2(const float* __restrict__ A,
                                                  float* __restrict__ chunkh) {
  int idx = blockIdx.x * 256 + threadIdx.x;  // 0..B*D-1
  int b = idx >> 10, d = idx & 1023;
  float dec = sigmoidf_(A[d]);
  float dL = dec;
#pragma unroll
  for (int i = 0; i < 6; ++i) dL *= dL;  // dec^64
  float hv[NC];
#pragma unroll
  for (int c = 0; c < NC; ++c) hv[c] = chunkh[(size_t)(b * NC + c) * DDIM + d];
  float carry = 0.f;
#pragma unroll
  for (int c = 0; c < NC; ++c) {
    float local = hv[c];
    hv[c] = carry;
    carry = fmaf(dL, carry, local);
  }
#pragma unroll
  for (int c = 0; c < NC; ++c) chunkh[(size_t)(b * NC + c) * DDIM + d] = hv[c];
}

__global__ __launch_bounds__(256) void ssm_phase3(const float* __restrict__ v,
                                                  const unsigned short* __restrict__ g,
                                                  const float* __restrict__ A,
                                                  const float* __restrict__ C,
                                                  const float* __restrict__ chunkh,
                                                  unsigned short* __restrict__ ybf) {
  int b = blockIdx.y, c = blockIdx.x;
  int d0 = threadIdx.x * 4;
  float4 a4 = *(const float4*)&A[d0];
  float4 c4 = *(const float4*)&C[d0];
  float dx = sigmoidf_(a4.x), dy = sigmoidf_(a4.y), dz = sigmoidf_(a4.z), dw = sigmoidf_(a4.w);
  float4 h0 = *(const float4*)&chunkh[(size_t)(b * NC + c) * DDIM + d0];
  float hx = h0.x, hy = h0.y, hz = h0.z, hw = h0.w;
  size_t base = ((size_t)b * TDIM + (size_t)c * LCH) * DDIM + d0;
  const float4* vp = (const float4*)(v + base);
  const ushort4* gp = (const ushort4*)(g + base);
  ushort4* yp = (ushort4*)(ybf + base);
#pragma unroll 4
  for (int i = 0; i < LCH; ++i) {
    float4 vv = vp[(size_t)i * (DDIM / 4)];
    ushort4 gg = gp[(size_t)i * (DDIM / 4)];
    hx = fmaf(dx, hx, vv.x);
    hy = fmaf(dy, hy, vv.y);
    hz = fmaf(dz, hz, vv.z);
    hw = fmaf(dw, hw, vv.w);
    ushort4 yy;
    yy.x = f2bf(bf2f(gg.x) * c4.x * hx);
    yy.y = f2bf(bf2f(gg.y) * c4.y * hy);
    yy.z = f2bf(bf2f(gg.z) * c4.z * hz);
    yy.w = f2bf(bf2f(gg.w) * c4.w * hw);
    yp[(size_t)i * (DDIM / 4)] = yy;
  }
}

extern "C" void kernel_launch(void* const* d_in, const int* in_sizes, int n_in,
                              void* d_out, int out_size, void* d_ws, size_t ws_size,
                              hipStream_t stream) {
  const float* x = (const float*)d_in[0];
  const float* W_in = (const float*)d_in[1];
  const float* b_in = (const float*)d_in[2];
  const float* A = (const float*)d_in[3];
  const float* C = (const float*)d_in[4];
  const float* W_out = (const float*)d_in[5];
  const float* b_out = (const float*)d_in[6];
  float* out = (float*)d_out;

  // workspace carve (~175 MB)
  char* ws = (char*)d_ws;
  const size_t MK = (size_t)MDIM * DDIM;  // 16,777,216
  unsigned short* xh = (unsigned short*)ws;    ws += MK * 2;                       // 33.5 MB
  unsigned short* winh = (unsigned short*)ws;  ws += (size_t)2 * DDIM * DDIM * 2;  // 4.2 MB
  unsigned short* wouth = (unsigned short*)ws; ws += (size_t)DDIM * DDIM * 2;      // 2.1 MB
  float* v = (float*)ws;                       ws += MK * 4;                       // 67.1 MB
  unsigned short* g = (unsigned short*)ws;     ws += MK * 2;                       // 33.5 MB
  unsigned short* ybf = (unsigned short*)ws;   ws += MK * 2;                       // 33.5 MB
  float* chunkh = (float*)ws;                  ws += (size_t)BDIM * NC * DDIM * 4; // 1.0 MB

  // prep
  prep_x_kernel<<<(int)(MK / 4 / 256), 256, 0, stream>>>(x, xh, (int)(MK / 4));
  wprep_kernel<<<dim3(2 * DDIM / 64, DDIM / 64), 256, 0, stream>>>(W_in, winh, DDIM, 2 * DDIM);
  wprep_kernel<<<dim3(DDIM / 64, DDIM / 64), 256, 0, stream>>>(W_out, wouth, DDIM, DDIM);

  // fused GEMM1: [v | g] = x @ W_in + b_in ; v f32, g = sigmoid -> bf16
  gemm8p<1><<<(MDIM / 256) * 8, 512, 0, stream>>>(xh, winh, b_in, v, g, 8, DDIM);

  // chunked scan
  ssm_phase1<<<dim3(NC, BDIM), 256, 0, stream>>>(v, A, chunkh);
  ssm_phase2<<<(BDIM * DDIM) / 256, 256, 0, stream>>>(A, chunkh);
  ssm_phase3<<<dim3(NC, BDIM), 256, 0, stream>>>(v, g, A, C, chunkh, ybf);

  // GEMM2: out = y @ W_out + b_out
  gemm8p<0><<<(MDIM / 256) * 4, 512, 0, stream>>>(ybf, wouth, b_out, out, nullptr, 4, DDIM);
}

// Round 3
// 186.569 us; speedup vs baseline: 1.5831x; 1.0932x over previous
//
#include <hip/hip_runtime.h>
#include <math.h>

// Problem dims (fixed by reference)
#define BDIM 4
#define TDIM 4096
#define DDIM 1024
#define MDIM (BDIM * TDIM)   // 16384

// scan chunking
#define NC  64
#define LCH 64
static_assert(NC * LCH == TDIM, "chunking");

typedef __attribute__((ext_vector_type(8))) short short8;
typedef __attribute__((ext_vector_type(4))) float f32x4;

__device__ __forceinline__ unsigned short f2bf(float f) {
  unsigned int u = __float_as_uint(f);
  unsigned int r = (u + 0x7fffu + ((u >> 16) & 1u)) >> 16;  // RNE
  return (unsigned short)r;
}
__device__ __forceinline__ float bf2f(unsigned short h) {
  return __uint_as_float(((unsigned int)h) << 16);
}
__device__ __forceinline__ float sigmoidf_(float x) {
  return 1.0f / (1.0f + expf(-x));
}

// ---------------- prep: x -> bf16 ----------------
__global__ __launch_bounds__(256) void prep_x_kernel(const float* __restrict__ x,
                                                     unsigned short* __restrict__ xh,
                                                     int n4) {
  int i = blockIdx.x * 256 + threadIdx.x;
  if (i >= n4) return;
  float4 f = ((const float4*)x)[i];
  ushort4 h;
  h.x = f2bf(f.x);
  h.y = f2bf(f.y);
  h.z = f2bf(f.z);
  h.w = f2bf(f.w);
  ((ushort4*)xh)[i] = h;
}

// ---------------- prep: W [K][N] f32 -> transposed [N][K] bf16 ----------------
__global__ __launch_bounds__(256) void wprep_kernel(const float* __restrict__ in,
                                                    unsigned short* __restrict__ oh,
                                                    int K, int N) {
  __shared__ float t[64][65];
  int n0 = blockIdx.x * 64;
  int k0 = blockIdx.y * 64;
#pragma unroll
  for (int i = 0; i < 16; ++i) {
    int idx = i * 256 + threadIdx.x;
    int r = idx >> 6, c = idx & 63;
    t[r][c] = in[(size_t)(k0 + r) * N + (n0 + c)];
  }
  __syncthreads();
#pragma unroll
  for (int i = 0; i < 16; ++i) {
    int idx = i * 256 + threadIdx.x;
    int rn = idx >> 6, ck = idx & 63;
    oh[(size_t)(n0 + rn) * K + (k0 + ck)] = f2bf(t[ck][rn]);
  }
}

// ---------------- 256x256 8-wave GEMM, BK=64, dbuf LDS, XOR-swizzled ----------------
// LDS tile: 256 rows x 64 cols bf16 = 32KB. Swizzle: byte ^= ((row&7)<<4).
// global_load_lds dest is LINEAR; source address carries the inverse swizzle
// (involution), reads apply the same XOR (rule 21: both-sides).

__device__ __forceinline__ void stage_tile(unsigned short* ldsTile,
                                           const unsigned short* __restrict__ gTile,
                                           int ldK) {
  int wave = threadIdx.x >> 6;
  int lane = threadIdx.x & 63;
#pragma unroll
  for (int half = 0; half < 2; ++half) {
#pragma unroll
    for (int j = 0; j < 2; ++j) {
      int c = wave * 64 + lane + j * 512;          // 16B-chunk index within half
      int Lt = half * 16384 + c * 16;              // within-tile linear byte
      int P = Lt ^ (((Lt >> 7) & 7) << 4);         // logical byte (row*128+colByte)
      const unsigned short* src = gTile + (size_t)(P >> 7) * ldK + ((P & 127) >> 1);
      // dest: wave-uniform base; HW adds lane*16
      unsigned short* dst = ldsTile + (half * 16384 + wave * 1024 + j * 8192) / 2;
      __builtin_amdgcn_global_load_lds(
          (const __attribute__((address_space(1))) unsigned int*)src,
          (__attribute__((address_space(3))) unsigned int*)dst, 16, 0, 0);
    }
  }
}

__device__ __forceinline__ short8 read_frag(const unsigned short* tile, int r, int kElem) {
  int addr = ((r << 7) + (kElem << 1)) ^ ((r & 7) << 4);
  return *(const short8*)((const char*)tile + addr);
}

#define BARRIER()                                  \
  do {                                             \
    asm volatile("" ::: "memory");                 \
    __builtin_amdgcn_s_barrier();                  \
    asm volatile("" ::: "memory");                 \
  } while (0)

#define READ_AF(SET, H, KKv)                                                    \
  _Pragma("unroll") for (int m = 0; m < 4; ++m)                                 \
      SET[m] = read_frag(As, rA + (H) * 64 + m * 16, (KKv) * 32 + kq);

#define READ_BF(KKv)                                                            \
  _Pragma("unroll") for (int n = 0; n < 4; ++n)                                 \
      bfr[n] = read_frag(Bs, rB + n * 16, (KKv) * 32 + kq);

#define MFMA16(SET, HH)                                                         \
  __builtin_amdgcn_s_setprio(1);                                                \
  _Pragma("unroll") for (int m = 0; m < 4; ++m)                                 \
      _Pragma("unroll") for (int n = 0; n < 4; ++n)                             \
          acc[(HH) * 4 + m][n] = __builtin_amdgcn_mfma_f32_16x16x32_bf16(       \
              SET[m], bfr[n], acc[(HH) * 4 + m][n], 0, 0, 0);                   \
  __builtin_amdgcn_s_setprio(0);

// EPI 0: f32 out + bias (N = nNt*256). EPI 1: fused v|g, both bf16, ld 1024
// (ntile<4 -> v = val, else g = sigmoid(val)).
template <int EPI>
__global__ __launch_bounds__(512, 2) void gemm8p(const unsigned short* __restrict__ A,
                                                 const unsigned short* __restrict__ B,
                                                 const float* __restrict__ bias,
                                                 float* __restrict__ outF,
                                                 unsigned short* __restrict__ outV,
                                                 unsigned short* __restrict__ outG,
                                                 int nNt, int K) {
  __shared__ unsigned short ldsA[2 * 16384];
  __shared__ unsigned short ldsB[2 * 16384];

  // T1: XCD-aware swizzle (gridDim.x % 8 == 0 for all our launches)
  int cpx = gridDim.x >> 3;
  int bid = blockIdx.x;
  int swz = (bid & 7) * cpx + (bid >> 3);
  int mtile = swz / nNt, ntile = swz % nNt;

  int wave = threadIdx.x >> 6, lane = threadIdx.x & 63;
  int wm = wave >> 2, wn = wave & 3;  // 2 x 4 waves, each 128x64 output
  int rA = wm * 128 + (lane & 15);
  int rB = wn * 64 + (lane & 15);
  int kq = (lane >> 4) * 8;

  const unsigned short* Ag = A + (size_t)(mtile * 256) * K;
  const unsigned short* Bg = B + (size_t)(ntile * 256) * K;

  f32x4 acc[8][4] = {};
  short8 afA[4], afB[4], bfr[4];

  // prologue: stage K-tile 0 into buf 0, full drain (once)
  stage_tile(ldsA, Ag, K);
  stage_tile(ldsB, Bg, K);
  asm volatile("s_waitcnt vmcnt(0)" ::: "memory");
  BARRIER();

  int NT = K >> 6;
  for (int t = 0; t < NT; ++t) {
    const unsigned short* As = ldsA + (t & 1) * 16384;
    const unsigned short* Bs = ldsB + (t & 1) * 16384;
    unsigned short* An = ldsA + ((t + 1) & 1) * 16384;
    unsigned short* Bn = ldsB + ((t + 1) & 1) * 16384;
    bool pf = (t + 1 < NT);
    int k1 = (t + 1) << 6;

    // R0: serial reads (cross-tile prefetch would race other waves' stages),
    // then MFMA overlapped with next-phase A-frag reads + A-stage.
    READ_AF(afA, 0, 0);
    READ_BF(0);
    MFMA16(afA, 0);
    READ_AF(afB, 1, 0);
    if (pf) stage_tile(An, Ag + k1, K);
    BARRIER();
    // R1: MFMA(kk0,H1) overlaps reads for kk1 (af + b) + B-stage.
    MFMA16(afB, 1);
    READ_AF(afA, 0, 1);
    READ_BF(1);
    if (pf) stage_tile(Bn, Bg + k1, K);
    BARRIER();
    // R2
    MFMA16(afA, 0);
    READ_AF(afB, 1, 1);
    BARRIER();
    // R3: MFMA only, then counted-ish drain at tile boundary.
    MFMA16(afB, 1);
    if (pf) asm volatile("s_waitcnt vmcnt(0)" ::: "memory");
    BARRIER();
  }

  // epilogue: C/D layout col = lane&15, row = (lane>>4)*4 + j
  int row0 = mtile * 256 + wm * 128 + ((lane >> 4) << 2);
  int col0 = ntile * 256 + wn * 64 + (lane & 15);
#pragma unroll
  for (int m = 0; m < 8; ++m) {
#pragma unroll
    for (int n = 0; n < 4; ++n) {
      int col = col0 + n * 16;
      float bv = bias[col];
#pragma unroll
      for (int j = 0; j < 4; ++j) {
        int row = row0 + m * 16 + j;
        float val = acc[m][n][j] + bv;
        if (EPI == 0) {
          outF[(size_t)row * (nNt * 256) + col] = val;
        } else {
          if (col < DDIM)
            outV[(size_t)row * DDIM + col] = f2bf(val);
          else
            outG[(size_t)row * DDIM + (col - DDIM)] = f2bf(sigmoidf_(val));
        }
      }
    }
  }
}

// ---------------- SSM chunked scan (v, g in bf16) ----------------
__global__ __launch_bounds__(256) void ssm_phase1(const unsigned short* __restrict__ v,
                                                  const float* __restrict__ A,
                                                  float* __restrict__ chunkh) {
  int b = blockIdx.y, c = blockIdx.x;
  int d0 = threadIdx.x * 4;
  float4 a4 = *(const float4*)&A[d0];
  float dx = sigmoidf_(a4.x), dy = sigmoidf_(a4.y), dz = sigmoidf_(a4.z), dw = sigmoidf_(a4.w);
  float hx = 0.f, hy = 0.f, hz = 0.f, hw = 0.f;
  const ushort4* vp = (const ushort4*)(v + ((size_t)b * TDIM + (size_t)c * LCH) * DDIM + d0);
#pragma unroll 4
  for (int i = 0; i < LCH; ++i) {
    ushort4 vv = vp[(size_t)i * (DDIM / 4)];
    hx = fmaf(dx, hx, bf2f(vv.x));
    hy = fmaf(dy, hy, bf2f(vv.y));
    hz = fmaf(dz, hz, bf2f(vv.z));
    hw = fmaf(dw, hw, bf2f(vv.w));
  }
  float4 o = {hx, hy, hz, hw};
  *(float4*)&chunkh[(size_t)(b * NC + c) * DDIM + d0] = o;
}

// phase 2: exclusive carry scan across chunks, bulk-loaded into registers.
__global__ __launch_bounds__(256) void ssm_phase2(const float* __restrict__ A,
                                                  float* __restrict__ chunkh) {
  int idx = blockIdx.x * 256 + threadIdx.x;  // 0..B*D-1
  int b = idx >> 10, d = idx & 1023;
  float dec = sigmoidf_(A[d]);
  float dL = dec;
#pragma unroll
  for (int i = 0; i < 6; ++i) dL *= dL;  // dec^64
  float hv[NC];
#pragma unroll
  for (int c = 0; c < NC; ++c) hv[c] = chunkh[(size_t)(b * NC + c) * DDIM + d];
  float carry = 0.f;
#pragma unroll
  for (int c = 0; c < NC; ++c) {
    float local = hv[c];
    hv[c] = carry;
    carry = fmaf(dL, carry, local);
  }
#pragma unroll
  for (int c = 0; c < NC; ++c) chunkh[(size_t)(b * NC + c) * DDIM + d] = hv[c];
}

__global__ __launch_bounds__(256) void ssm_phase3(const unsigned short* __restrict__ v,
                                                  const unsigned short* __restrict__ g,
                                                  const float* __restrict__ A,
                                                  const float* __restrict__ C,
                                                  const float* __restrict__ chunkh,
                                                  unsigned short* __restrict__ ybf) {
  int b = blockIdx.y, c = blockIdx.x;
  int d0 = threadIdx.x * 4;
  float4 a4 = *(const float4*)&A[d0];
  float4 c4 = *(const float4*)&C[d0];
  float dx = sigmoidf_(a4.x), dy = sigmoidf_(a4.y), dz = sigmoidf_(a4.z), dw = sigmoidf_(a4.w);
  float4 h0 = *(const float4*)&chunkh[(size_t)(b * NC + c) * DDIM + d0];
  float hx = h0.x, hy = h0.y, hz = h0.z, hw = h0.w;
  size_t base = ((size_t)b * TDIM + (size_t)c * LCH) * DDIM + d0;
  const ushort4* vp = (const ushort4*)(v + base);
  const ushort4* gp = (const ushort4*)(g + base);
  ushort4* yp = (ushort4*)(ybf + base);
#pragma unroll 4
  for (int i = 0; i < LCH; ++i) {
    ushort4 vv = vp[(size_t)i * (DDIM / 4)];
    ushort4 gg = gp[(size_t)i * (DDIM / 4)];
    hx = fmaf(dx, hx, bf2f(vv.x));
    hy = fmaf(dy, hy, bf2f(vv.y));
    hz = fmaf(dz, hz, bf2f(vv.z));
    hw = fmaf(dw, hw, bf2f(vv.w));
    ushort4 yy;
    yy.x = f2bf(bf2f(gg.x) * c4.x * hx);
    yy.y = f2bf(bf2f(gg.y) * c4.y * hy);
    yy.z = f2bf(bf2f(gg.z) * c4.z * hz);
    yy.w = f2bf(bf2f(gg.w) * c4.w * hw);
    yp[(size_t)i * (DDIM / 4)] = yy;
  }
}

extern "C" void kernel_launch(void* const* d_in, const int* in_sizes, int n_in,
                              void* d_out, int out_size, void* d_ws, size_t ws_size,
                              hipStream_t stream) {
  const float* x = (const float*)d_in[0];
  const float* W_in = (const float*)d_in[1];
  const float* b_in = (const float*)d_in[2];
  const float* A = (const float*)d_in[3];
  const float* C = (const float*)d_in[4];
  const float* W_out = (const float*)d_in[5];
  const float* b_out = (const float*)d_in[6];
  float* out = (float*)d_out;

  // workspace carve (~142 MB)
  char* ws = (char*)d_ws;
  const size_t MK = (size_t)MDIM * DDIM;  // 16,777,216
  unsigned short* xh = (unsigned short*)ws;    ws += MK * 2;                       // 33.5 MB
  unsigned short* winh = (unsigned short*)ws;  ws += (size_t)2 * DDIM * DDIM * 2;  // 4.2 MB
  unsigned short* wouth = (unsigned short*)ws; ws += (size_t)DDIM * DDIM * 2;      // 2.1 MB
  unsigned short* v = (unsigned short*)ws;     ws += MK * 2;                       // 33.5 MB
  unsigned short* g = (unsigned short*)ws;     ws += MK * 2;                       // 33.5 MB
  unsigned short* ybf = (unsigned short*)ws;   ws += MK * 2;                       // 33.5 MB
  float* chunkh = (float*)ws;                  ws += (size_t)BDIM * NC * DDIM * 4; // 1.0 MB

  // prep
  prep_x_kernel<<<(int)(MK / 4 / 256), 256, 0, stream>>>(x, xh, (int)(MK / 4));
  wprep_kernel<<<dim3(2 * DDIM / 64, DDIM / 64), 256, 0, stream>>>(W_in, winh, DDIM, 2 * DDIM);
  wprep_kernel<<<dim3(DDIM / 64, DDIM / 64), 256, 0, stream>>>(W_out, wouth, DDIM, DDIM);

  // fused GEMM1: [v | g] = x @ W_in + b_in ; v bf16, g = sigmoid -> bf16
  gemm8p<1><<<(MDIM / 256) * 8, 512, 0, stream>>>(xh, winh, b_in, nullptr, v, g, 8, DDIM);

  // chunked scan
  ssm_phase1<<<dim3(NC, BDIM), 256, 0, stream>>>(v, A, chunkh);
  ssm_phase2<<<(BDIM * DDIM) / 256, 256, 0, stream>>>(A, chunkh);
  ssm_phase3<<<dim3(NC, BDIM), 256, 0, stream>>>(v, g, A, C, chunkh, ybf);

  // GEMM2: out = y @ W_out + b_out
  gemm8p<0><<<(MDIM / 256) * 4, 512, 0, stream>>>(ybf, wouth, b_out, out, nullptr, nullptr,
                                                  4, DDIM);
}

// Round 5
// 180.405 us; speedup vs baseline: 1.6372x; 1.0342x over previous
//
#include <hip/hip_runtime.h>
#include <math.h>

// Problem dims (fixed by reference)
#define BDIM 4
#define TDIM 4096
#define DDIM 1024
#define MDIM (BDIM * TDIM)   // 16384

// scan chunking
#define NC  64
#define LCH 64
static_assert(NC * LCH == TDIM, "chunking");

typedef __attribute__((ext_vector_type(8))) short short8;
typedef __attribute__((ext_vector_type(4))) float f32x4;

__device__ __forceinline__ unsigned short f2bf(float f) {
  unsigned int u = __float_as_uint(f);
  unsigned int r = (u + 0x7fffu + ((u >> 16) & 1u)) >> 16;  // RNE
  return (unsigned short)r;
}
__device__ __forceinline__ float bf2f(unsigned short h) {
  return __uint_as_float(((unsigned int)h) << 16);
}
__device__ __forceinline__ float sigmoidf_(float x) {
  return 1.0f / (1.0f + expf(-x));
}

// ---------------- prep: x -> bf16 ----------------
__global__ __launch_bounds__(256) void prep_x_kernel(const float* __restrict__ x,
                                                     unsigned short* __restrict__ xh,
                                                     int n4) {
  int i = blockIdx.x * 256 + threadIdx.x;
  if (i >= n4) return;
  float4 f = ((const float4*)x)[i];
  ushort4 h;
  h.x = f2bf(f.x);
  h.y = f2bf(f.y);
  h.z = f2bf(f.z);
  h.w = f2bf(f.w);
  ((ushort4*)xh)[i] = h;
}

// ---------------- prep: W [K][N] f32 -> transposed [N][K] bf16 ----------------
__global__ __launch_bounds__(256) void wprep_kernel(const float* __restrict__ in,
                                                    unsigned short* __restrict__ oh,
                                                    int K, int N) {
  __shared__ float t[64][65];
  int n0 = blockIdx.x * 64;
  int k0 = blockIdx.y * 64;
#pragma unroll
  for (int i = 0; i < 16; ++i) {
    int idx = i * 256 + threadIdx.x;
    int r = idx >> 6, c = idx & 63;
    t[r][c] = in[(size_t)(k0 + r) * N + (n0 + c)];
  }
  __syncthreads();
#pragma unroll
  for (int i = 0; i < 16; ++i) {
    int idx = i * 256 + threadIdx.x;
    int rn = idx >> 6, ck = idx & 63;
    oh[(size_t)(n0 + rn) * K + (k0 + ck)] = f2bf(t[ck][rn]);
  }
}

// ---------------- 256x256 8-wave GEMM, BK=64, dbuf LDS, XOR-swizzled ----------------
// Each staged tile = 256 rows x 128 B = 32768 BYTES.
// LDS layout (bytes): A-buf0 @0, A-buf1 @32768, B-buf0 @65536, B-buf1 @98304.
// Swizzle: physical = logical ^ ((row&7)<<4)  (involution, bits 4-6 only).
// global_load_lds writes LINEARLY; the source address carries the inverse swizzle.
// All ds_read addresses = per-thread base VGPR + compile-time immediate
// (buffer select via K-loop unroll-by-2).

#define BARRIER()                                  \
  do {                                             \
    asm volatile("" ::: "memory");                 \
    __builtin_amdgcn_s_barrier();                  \
    asm volatile("" ::: "memory");                 \
  } while (0)

#define RD_A(SET, BUFC, H, BK)                                                  \
  _Pragma("unroll") for (int m = 0; m < 4; ++m)                                 \
      SET[m] = *(const short8*)(ldsb + (((BK) ? baseA1 : baseA0) + (BUFC) +     \
                                        (H) * 8192 + m * 2048));

#define RD_B(SET, BUFC, BK)                                                     \
  _Pragma("unroll") for (int n = 0; n < 4; ++n)                                 \
      SET[n] = *(const short8*)(ldsbB + (((BK) ? baseB1 : baseB0) + (BUFC) +    \
                                         n * 2048));

#define MFMA16(ASET, BSET, HH)                                                  \
  __builtin_amdgcn_s_setprio(1);                                                \
  _Pragma("unroll") for (int m = 0; m < 4; ++m)                                 \
      _Pragma("unroll") for (int n = 0; n < 4; ++n)                             \
          acc[(HH) * 4 + m][n] = __builtin_amdgcn_mfma_f32_16x16x32_bf16(       \
              ASET[m], BSET[n], acc[(HH) * 4 + m][n], 0, 0, 0);                 \
  __builtin_amdgcn_s_setprio(0);

// one staging load: 16B per lane, dst = wave-uniform LDS base (+lane*16 by HW)
#define STAGE(PTR, S, BUFB, KOFF)                                               \
  __builtin_amdgcn_global_load_lds(                                             \
      (const __attribute__((address_space(1))) unsigned int*)((PTR) + off##S +  \
                                                              (KOFF)),         \
      (__attribute__((address_space(3))) unsigned int*)((char*)lds + (BUFB) +   \
                                                        (S) * 8192 +            \
                                                        wave * 1024),           \
      16, 0, 0);

// one K-tile: 4 MFMA clusters, frag-reads interleaved, stages for t+1
// front-loaded, single vmcnt(0)+barrier at the tail.
#define TILE(T, BUFC, BUFN)                                                     \
  {                                                                             \
    bool pf = ((T) + 1 < NT);                                                   \
    int k1 = ((T) + 1) << 7; /* byte advance: 64 elems * 2B per tile */         \
    RD_A(afA, BUFC, 0, 0);                                                      \
    RD_B(bfrA, BUFC, 0);                                                        \
    if (pf) {                                                                   \
      STAGE(AgB, 0, BUFN, k1) STAGE(AgB, 1, BUFN, k1)                           \
      STAGE(AgB, 2, BUFN, k1) STAGE(AgB, 3, BUFN, k1)                           \
    }                                                                           \
    RD_A(afB, BUFC, 1, 0);                                                      \
    MFMA16(afA, bfrA, 0);                                                       \
    if (pf) { STAGE(BgB, 0, 65536 + (BUFN), k1) STAGE(BgB, 1, 65536 + (BUFN), k1) } \
    RD_A(afA, BUFC, 0, 1);                                                      \
    RD_B(bfrB, BUFC, 1);                                                        \
    MFMA16(afB, bfrA, 1);                                                       \
    if (pf) { STAGE(BgB, 2, 65536 + (BUFN), k1) STAGE(BgB, 3, 65536 + (BUFN), k1) } \
    RD_A(afB, BUFC, 1, 1);                                                      \
    MFMA16(afA, bfrB, 0);                                                       \
    MFMA16(afB, bfrB, 1);                                                       \
    if (pf) asm volatile("s_waitcnt vmcnt(0)" ::: "memory");                    \
    BARRIER();                                                                  \
  }

// EPI 0: f32 out + bias (N = nNt*256). EPI 1: fused v|g, both bf16, ld 1024
// (col<D -> v = val, else g = sigmoid(val)).
template <int EPI>
__global__ __launch_bounds__(512, 2) void gemm8p(const unsigned short* __restrict__ A,
                                                 const unsigned short* __restrict__ B,
                                                 const float* __restrict__ bias,
                                                 float* __restrict__ outF,
                                                 unsigned short* __restrict__ outV,
                                                 unsigned short* __restrict__ outG,
                                                 int nNt, int K) {
  __shared__ unsigned short lds[65536];  // 128 KiB

  // T1: XCD-aware swizzle (gridDim.x % 8 == 0 for all our launches)
  int cpx = gridDim.x >> 3;
  int bid = blockIdx.x;
  int swz = (bid & 7) * cpx + (bid >> 3);
  int mtile = swz / nNt, ntile = swz % nNt;

  int tid = threadIdx.x;
  int wave = tid >> 6, lane = tid & 63;
  int wm = wave >> 2, wn = wave & 3;  // 2 x 4 waves, each 128x64 output
  int rA = wm * 128 + (lane & 15);
  int rB = wn * 64 + (lane & 15);
  int kq2 = (lane >> 4) * 16;  // k-quad offset in BYTES

  // hoisted swizzled read bases (all read addrs = base + compile-time imm)
  int baseA0 = ((rA << 7) + kq2) ^ ((rA & 7) << 4);
  int baseA1 = ((rA << 7) + kq2 + 64) ^ ((rA & 7) << 4);
  int baseB0 = ((rB << 7) + kq2) ^ ((rB & 7) << 4);
  int baseB1 = ((rB << 7) + kq2 + 64) ^ ((rB & 7) << 4);
  const char* ldsb = (const char*)lds;
  const char* ldsbB = (const char*)lds + 65536;

  // hoisted staging source offsets (inverse swizzle; same geometry A and B)
#define MKOFF(S) \
  ({ int Lt = (S) * 8192 + tid * 16; int P = Lt ^ (((Lt >> 7) & 7) << 4); \
     ((P >> 7) * (K << 1)) + (P & 127); })
  int off0 = MKOFF(0), off1 = MKOFF(1), off2 = MKOFF(2), off3 = MKOFF(3);
#undef MKOFF

  const char* AgB = (const char*)(A + (size_t)(mtile * 256) * K);
  const char* BgB = (const char*)(B + (size_t)(ntile * 256) * K);

  f32x4 acc[8][4] = {};
  short8 afA[4], afB[4], bfrA[4], bfrB[4];

  // prologue: stage K-tile 0 into buf0, full drain (once)
  STAGE(AgB, 0, 0, 0) STAGE(AgB, 1, 0, 0) STAGE(AgB, 2, 0, 0) STAGE(AgB, 3, 0, 0)
  STAGE(BgB, 0, 65536, 0) STAGE(BgB, 1, 65536, 0)
  STAGE(BgB, 2, 65536, 0) STAGE(BgB, 3, 65536, 0)
  asm volatile("s_waitcnt vmcnt(0)" ::: "memory");
  BARRIER();

  int NT = K >> 6;  // 16 (even)
  for (int t = 0; t < NT; t += 2) {
    TILE(t, 0, 32768)
    TILE(t + 1, 32768, 0)
  }

  // epilogue: C/D layout col = lane&15, row = (lane>>4)*4 + j
  int row0 = mtile * 256 + wm * 128 + ((lane >> 4) << 2);
  int col0 = ntile * 256 + wn * 64 + (lane & 15);
#pragma unroll
  for (int m = 0; m < 8; ++m) {
#pragma unroll
    for (int n = 0; n < 4; ++n) {
      int col = col0 + n * 16;
      float bv = bias[col];
#pragma unroll
      for (int j = 0; j < 4; ++j) {
        int row = row0 + m * 16 + j;
        float val = acc[m][n][j] + bv;
        if (EPI == 0) {
          outF[(size_t)row * (nNt * 256) + col] = val;
        } else {
          if (col < DDIM)
            outV[(size_t)row * DDIM + col] = f2bf(val);
          else
            outG[(size_t)row * DDIM + (col - DDIM)] = f2bf(sigmoidf_(val));
        }
      }
    }
  }
}

// ---------------- SSM chunked scan (v, g in bf16) ----------------
__global__ __launch_bounds__(256) void ssm_phase1(const unsigned short* __restrict__ v,
                                                  const float* __restrict__ A,
                                                  float* __restrict__ chunkh) {
  int b = blockIdx.y, c = blockIdx.x;
  int d0 = threadIdx.x * 4;
  float4 a4 = *(const float4*)&A[d0];
  float dx = sigmoidf_(a4.x), dy = sigmoidf_(a4.y), dz = sigmoidf_(a4.z), dw = sigmoidf_(a4.w);
  float hx = 0.f, hy = 0.f, hz = 0.f, hw = 0.f;
  const ushort4* vp = (const ushort4*)(v + ((size_t)b * TDIM + (size_t)c * LCH) * DDIM + d0);
#pragma unroll 4
  for (int i = 0; i < LCH; ++i) {
    ushort4 vv = vp[(size_t)i * (DDIM / 4)];
    hx = fmaf(dx, hx, bf2f(vv.x));
    hy = fmaf(dy, hy, bf2f(vv.y));
    hz = fmaf(dz, hz, bf2f(vv.z));
    hw = fmaf(dw, hw, bf2f(vv.w));
  }
  float4 o = {hx, hy, hz, hw};
  *(float4*)&chunkh[(size_t)(b * NC + c) * DDIM + d0] = o;
}

// phase 2: exclusive carry scan across chunks, bulk-loaded into registers.
__global__ __launch_bounds__(256) void ssm_phase2(const float* __restrict__ A,
                                                  float* __restrict__ chunkh) {
  int idx = blockIdx.x * 256 + threadIdx.x;  // 0..B*D-1
  int b = idx >> 10, d = idx & 1023;
  float dec = sigmoidf_(A[d]);
  float dL = dec;
#pragma unroll
  for (int i = 0; i < 6; ++i) dL *= dL;  // dec^64
  float hv[NC];
#pragma unroll
  for (int c = 0; c < NC; ++c) hv[c] = chunkh[(size_t)(b * NC + c) * DDIM + d];
  float carry = 0.f;
#pragma unroll
  for (int c = 0; c < NC; ++c) {
    float local = hv[c];
    hv[c] = carry;
    carry = fmaf(dL, carry, local);
  }
#pragma unroll
  for (int c = 0; c < NC; ++c) chunkh[(size_t)(b * NC + c) * DDIM + d] = hv[c];
}

__global__ __launch_bounds__(256) void ssm_phase3(const unsigned short* __restrict__ v,
                                                  const unsigned short* __restrict__ g,
                                                  const float* __restrict__ A,
                                                  const float* __restrict__ C,
                                                  const float* __restrict__ chunkh,
                                                  unsigned short* __restrict__ ybf) {
  int b = blockIdx.y, c = blockIdx.x;
  int d0 = threadIdx.x * 4;
  float4 a4 = *(const float4*)&A[d0];
  float4 c4 = *(const float4*)&C[d0];
  float dx = sigmoidf_(a4.x), dy = sigmoidf_(a4.y), dz = sigmoidf_(a4.z), dw = sigmoidf_(a4.w);
  float4 h0 = *(const float4*)&chunkh[(size_t)(b * NC + c) * DDIM + d0];
  float hx = h0.x, hy = h0.y, hz = h0.z, hw = h0.w;
  size_t base = ((size_t)b * TDIM + (size_t)c * LCH) * DDIM + d0;
  const ushort4* vp = (const ushort4*)(v + base);
  const ushort4* gp = (const ushort4*)(g + base);
  ushort4* yp = (ushort4*)(ybf + base);
#pragma unroll 4
  for (int i = 0; i < LCH; ++i) {
    ushort4 vv = vp[(size_t)i * (DDIM / 4)];
    ushort4 gg = gp[(size_t)i * (DDIM / 4)];
    hx = fmaf(dx, hx, bf2f(vv.x));
    hy = fmaf(dy, hy, bf2f(vv.y));
    hz = fmaf(dz, hz, bf2f(vv.z));
    hw = fmaf(dw, hw, bf2f(vv.w));
    ushort4 yy;
    yy.x = f2bf(bf2f(gg.x) * c4.x * hx);
    yy.y = f2bf(bf2f(gg.y) * c4.y * hy);
    yy.z = f2bf(bf2f(gg.z) * c4.z * hz);
    yy.w = f2bf(bf2f(gg.w) * c4.w * hw);
    yp[(size_t)i * (DDIM / 4)] = yy;
  }
}

extern "C" void kernel_launch(void* const* d_in, const int* in_sizes, int n_in,
                              void* d_out, int out_size, void* d_ws, size_t ws_size,
                              hipStream_t stream) {
  const float* x = (const float*)d_in[0];
  const float* W_in = (const float*)d_in[1];
  const float* b_in = (const float*)d_in[2];
  const float* A = (const float*)d_in[3];
  const float* C = (const float*)d_in[4];
  const float* W_out = (const float*)d_in[5];
  const float* b_out = (const float*)d_in[6];
  float* out = (float*)d_out;

  // workspace carve (~142 MB)
  char* ws = (char*)d_ws;
  const size_t MK = (size_t)MDIM * DDIM;  // 16,777,216
  unsigned short* xh = (unsigned short*)ws;    ws += MK * 2;                       // 33.5 MB
  unsigned short* winh = (unsigned short*)ws;  ws += (size_t)2 * DDIM * DDIM * 2;  // 4.2 MB
  unsigned short* wouth = (unsigned short*)ws; ws += (size_t)DDIM * DDIM * 2;      // 2.1 MB
  unsigned short* v = (unsigned short*)ws;     ws += MK * 2;                       // 33.5 MB
  unsigned short* g = (unsigned short*)ws;     ws += MK * 2;                       // 33.5 MB
  unsigned short* ybf = (unsigned short*)ws;   ws += MK * 2;                       // 33.5 MB
  float* chunkh = (float*)ws;                  ws += (size_t)BDIM * NC * DDIM * 4; // 1.0 MB

  // prep
  prep_x_kernel<<<(int)(MK / 4 / 256), 256, 0, stream>>>(x, xh, (int)(MK / 4));
  wprep_kernel<<<dim3(2 * DDIM / 64, DDIM / 64), 256, 0, stream>>>(W_in, winh, DDIM, 2 * DDIM);
  wprep_kernel<<<dim3(DDIM / 64, DDIM / 64), 256, 0, stream>>>(W_out, wouth, DDIM, DDIM);

  // fused GEMM1: [v | g] = x @ W_in + b_in ; v bf16, g = sigmoid -> bf16
  gemm8p<1><<<(MDIM / 256) * 8, 512, 0, stream>>>(xh, winh, b_in, nullptr, v, g, 8, DDIM);

  // chunked scan
  ssm_phase1<<<dim3(NC, BDIM), 256, 0, stream>>>(v, A, chunkh);
  ssm_phase2<<<(BDIM * DDIM) / 256, 256, 0, stream>>>(A, chunkh);
  ssm_phase3<<<dim3(NC, BDIM), 256, 0, stream>>>(v, g, A, C, chunkh, ybf);

  // GEMM2: out = y @ W_out + b_out
  gemm8p<0><<<(MDIM / 256) * 4, 512, 0, stream>>>(ybf, wouth, b_out, out, nullptr, nullptr,
                                                  4, DDIM);
}